// Round 1
// baseline (71.080 us; speedup 1.0000x reference)
//
#include <hip/hip_runtime.h>

#define EMBED 512
#define HID 16
#define TPB 16     // tokens per block
#define TPW 4      // tokens per wave
#define CROWS 256  // fc2_w rows per LDS chunk (16 KB)
#define XROW (EMBED + 4)   // padded LDS row for x (breaks 2KB-stride bank aliasing)

// XOR swizzle on float4 index within a 1024-float4 chunk; involution.
// Spreads byte bits [6:4] (bank-group bits) with lane-varying row bits.
__device__ __forceinline__ int swz(int idx4) { return idx4 ^ ((idx4 >> 4) & 7); }

__global__ __launch_bounds__(256, 2)
void hyper_fused(const float* __restrict__ x,
                 const float* __restrict__ fc1w,
                 const float* __restrict__ fc1b,
                 const float* __restrict__ fc2w,
                 const float* __restrict__ fc2b,
                 float* __restrict__ out)
{
    __shared__ float  xs[TPB][XROW];       // 33 KB
    __shared__ float  hs[TPB][HID];        // 1 KB
    __shared__ float4 ws[CROWS * 4];       // 16 KB, swizzled slots

    const int tid  = threadIdx.x;
    const int lane = tid & 63;
    const int wv   = tid >> 6;
    const long tok0 = (long)blockIdx.x * TPB;

    // ---------------- stage x (16 tokens x 512 f32, coalesced float4) --------
    {
        const float4* xg = reinterpret_cast<const float4*>(x + tok0 * EMBED);
        #pragma unroll
        for (int i = 0; i < 8; ++i) {
            int idx = tid + i * 256;          // 2048 float4 total
            float4 v = xg[idx];
            int t  = idx >> 7;                // 128 float4 per token
            int e4 = idx & 127;
            *reinterpret_cast<float4*>(&xs[t][e4 * 4]) = v;
        }
    }
    __syncthreads();

    // ---------------- fc1: thread (t = tid>>4, k = tid&15) -------------------
    {
        const int ht = tid >> 4, hk = tid & 15;
        const float4* wr = reinterpret_cast<const float4*>(fc1w + hk * EMBED);
        float acc = fc1b[hk];
        #pragma unroll 4
        for (int i = 0; i < 128; ++i) {
            float4 w4 = wr[i];
            float4 x4 = *reinterpret_cast<const float4*>(&xs[ht][i * 4]);
            acc = fmaf(w4.x, x4.x, acc);
            acc = fmaf(w4.y, x4.y, acc);
            acc = fmaf(w4.z, x4.z, acc);
            acc = fmaf(w4.w, x4.w, acc);
        }
        hs[ht][hk] = fmaxf(acc, 0.0f);
    }
    __syncthreads();

    // ---------------- load h for this wave's 4 tokens into regs --------------
    float h[TPW][HID];
    #pragma unroll
    for (int tt = 0; tt < TPW; ++tt) {
        #pragma unroll
        for (int k4 = 0; k4 < 4; ++k4) {
            float4 hv = *reinterpret_cast<const float4*>(&hs[wv * TPW + tt][k4 * 4]);
            h[tt][k4 * 4 + 0] = hv.x;
            h[tt][k4 * 4 + 1] = hv.y;
            h[tt][k4 * 4 + 2] = hv.z;
            h[tt][k4 * 4 + 3] = hv.w;
        }
    }

    // ---------------- w1 phase: y1[t][j] = sum_e x[e] * (row(e*4+j)·h + b) ---
    float y1[TPW][4] = {{0.f, 0.f, 0.f, 0.f}};
    #pragma unroll 1
    for (int c = 0; c < 8; ++c) {
        __syncthreads();
        const float4* wg = reinterpret_cast<const float4*>(fc2w) + c * (CROWS * 4);
        #pragma unroll
        for (int i = 0; i < 4; ++i) {
            int d = tid + i * 256;
            ws[d] = wg[swz(d)];               // linear LDS dest, inv-swz source
        }
        __syncthreads();

        const int e = c * 64 + lane;
        float xv[TPW];
        #pragma unroll
        for (int tt = 0; tt < TPW; ++tt) xv[tt] = xs[wv * TPW + tt][e];
        const float4 bv = reinterpret_cast<const float4*>(fc2b)[e];

        #pragma unroll
        for (int j = 0; j < 4; ++j) {
            const int rbase = (lane * 4 + j) * 4;     // float4 idx of row in chunk
            float4 r0 = ws[swz(rbase + 0)];
            float4 r1 = ws[swz(rbase + 1)];
            float4 r2 = ws[swz(rbase + 2)];
            float4 r3 = ws[swz(rbase + 3)];
            const float bias = (j == 0) ? bv.x : (j == 1) ? bv.y : (j == 2) ? bv.z : bv.w;
            #pragma unroll
            for (int tt = 0; tt < TPW; ++tt) {
                float d0 = bias;
                d0 = fmaf(r0.x, h[tt][0],  d0); d0 = fmaf(r0.y, h[tt][1],  d0);
                d0 = fmaf(r0.z, h[tt][2],  d0); d0 = fmaf(r0.w, h[tt][3],  d0);
                d0 = fmaf(r1.x, h[tt][4],  d0); d0 = fmaf(r1.y, h[tt][5],  d0);
                d0 = fmaf(r1.z, h[tt][6],  d0); d0 = fmaf(r1.w, h[tt][7],  d0);
                d0 = fmaf(r2.x, h[tt][8],  d0); d0 = fmaf(r2.y, h[tt][9],  d0);
                d0 = fmaf(r2.z, h[tt][10], d0); d0 = fmaf(r2.w, h[tt][11], d0);
                d0 = fmaf(r3.x, h[tt][12], d0); d0 = fmaf(r3.y, h[tt][13], d0);
                d0 = fmaf(r3.z, h[tt][14], d0); d0 = fmaf(r3.w, h[tt][15], d0);
                y1[tt][j] = fmaf(xv[tt], d0, y1[tt][j]);
            }
        }
    }

    // reduce y1 across the wave's 64 lanes (each lane summed disjoint e's)
    #pragma unroll
    for (int tt = 0; tt < TPW; ++tt) {
        #pragma unroll
        for (int j = 0; j < 4; ++j) {
            float v = y1[tt][j];
            #pragma unroll
            for (int off = 32; off; off >>= 1) v += __shfl_xor(v, off, 64);
            y1[tt][j] = fmaxf(v, 0.0f);       // relu(y1), all lanes hold it
        }
    }

    // ---------------- w2 phase: y[t][e] = relu(sum_j y1[t][j]*(row·h + b)) ---
    float yacc[TPW][8] = {};
    #pragma unroll
    for (int j = 0; j < 4; ++j) {
        #pragma unroll
        for (int half = 0; half < 2; ++half) {
            __syncthreads();
            const int c = j * 2 + half;       // chunk: rows 2048 + c*256 ...
            const float4* wg = reinterpret_cast<const float4*>(fc2w) + 8192 + c * 1024;
            #pragma unroll
            for (int i = 0; i < 4; ++i) {
                int d = tid + i * 256;
                ws[d] = wg[swz(d)];
            }
            __syncthreads();

            #pragma unroll
            for (int i = 0; i < 4; ++i) {
                const int rloc  = i * 64 + lane;          // row within chunk
                const int rbase = rloc * 4;
                float4 r0 = ws[swz(rbase + 0)];
                float4 r1 = ws[swz(rbase + 1)];
                float4 r2 = ws[swz(rbase + 2)];
                float4 r3 = ws[swz(rbase + 3)];
                const int e = half * 256 + i * 64 + lane;
                const float bias = fc2b[2048 + j * 512 + e];
                #pragma unroll
                for (int tt = 0; tt < TPW; ++tt) {
                    float d0 = bias;
                    d0 = fmaf(r0.x, h[tt][0],  d0); d0 = fmaf(r0.y, h[tt][1],  d0);
                    d0 = fmaf(r0.z, h[tt][2],  d0); d0 = fmaf(r0.w, h[tt][3],  d0);
                    d0 = fmaf(r1.x, h[tt][4],  d0); d0 = fmaf(r1.y, h[tt][5],  d0);
                    d0 = fmaf(r1.z, h[tt][6],  d0); d0 = fmaf(r1.w, h[tt][7],  d0);
                    d0 = fmaf(r2.x, h[tt][8],  d0); d0 = fmaf(r2.y, h[tt][9],  d0);
                    d0 = fmaf(r2.z, h[tt][10], d0); d0 = fmaf(r2.w, h[tt][11], d0);
                    d0 = fmaf(r3.x, h[tt][12], d0); d0 = fmaf(r3.y, h[tt][13], d0);
                    d0 = fmaf(r3.z, h[tt][14], d0); d0 = fmaf(r3.w, h[tt][15], d0);
                    yacc[tt][half * 4 + i] = fmaf(y1[tt][j], d0, yacc[tt][half * 4 + i]);
                }
            }
        }
    }

    // ---------------- relu + store (coalesced per (token, slot)) -------------
    #pragma unroll
    for (int tt = 0; tt < TPW; ++tt) {
        const long trow = (tok0 + wv * TPW + tt) * EMBED;
        #pragma unroll
        for (int s = 0; s < 8; ++s) {
            const int e = (s >> 2) * 256 + (s & 3) * 64 + lane;
            out[trow + e] = fmaxf(yacc[tt][s], 0.0f);
        }
    }
}

extern "C" void kernel_launch(void* const* d_in, const int* in_sizes, int n_in,
                              void* d_out, int out_size, void* d_ws, size_t ws_size,
                              hipStream_t stream) {
    const float* x    = (const float*)d_in[0];
    const float* fc1w = (const float*)d_in[1];
    const float* fc1b = (const float*)d_in[2];
    const float* fc2w = (const float*)d_in[3];
    const float* fc2b = (const float*)d_in[4];
    float* out = (float*)d_out;
    hyper_fused<<<dim3(8192 / TPB), dim3(256), 0, stream>>>(x, fc1w, fc1b, fc2w, fc2b, out);
}

// Round 2
// 50.849 us; speedup vs baseline: 1.3979x; 1.3979x over previous
//
#include <hip/hip_runtime.h>

#define EMBED 512
#define HID 16
#define NTOK 8192
#define TG 64            // tokens per group (lane = token)
#define WPB 16           // waves per block (1024 threads)
#define ESL 16           // e-slice per wave per half

// f32 -> bf16 bits (round-nearest-even) and back
__device__ __forceinline__ unsigned f2b(float f) {
    unsigned u = __float_as_uint(f);
    return (u + 0x7FFFu + ((u >> 16) & 1u)) >> 16;
}
__device__ __forceinline__ float b2f(unsigned b) { return __uint_as_float(b << 16); }

// ---------------------------------------------------------------------------
// K12: fc1 (full h per 64-token group) + w1 partial (this block's e-half)
// grid 256 = (group g, e-half eh); block 1024 = 16 waves x 64 lanes(=tokens)
// ---------------------------------------------------------------------------
__global__ __launch_bounds__(1024, 4)
void k12(const float* __restrict__ x, const float* __restrict__ fc1w,
         const float* __restrict__ fc1b, const float* __restrict__ fc2w,
         const float* __restrict__ fc2b, float* __restrict__ hbuf,
         float* __restrict__ y1p)
{
    __shared__ unsigned red[WPB * 64 * 9];   // 36.9 KB: bf16-pair h partials; reused as f32 y1 partials [16][64][5]
    __shared__ float hs[64 * 17];            // 4.3 KB: reduced h

    const int tid = threadIdx.x;
    const int t   = tid & 63;
    const int wv  = __builtin_amdgcn_readfirstlane(tid >> 6);  // wave id, provably uniform
    const int g   = blockIdx.x >> 1;
    const int eh  = blockIdx.x & 1;
    const long tok = (long)g * TG + t;

    // ---- per-lane x slices: A = [16*wv, +16), B = [256+16*wv, +16) ----------
    float4 xa[4], xb[4];
    {
        const float4* xp = reinterpret_cast<const float4*>(x + tok * EMBED);
        #pragma unroll
        for (int c = 0; c < 4; ++c) xa[c] = xp[wv * 4 + c];
        #pragma unroll
        for (int c = 0; c < 4; ++c) xb[c] = xp[64 + wv * 4 + c];
    }

    // ---- fc1 partial: hk[k] = sum over this wave's 32 e's -------------------
    float hk[16];
    #pragma unroll
    for (int k = 0; k < 16; ++k) hk[k] = 0.f;
    #pragma unroll
    for (int k = 0; k < 16; ++k) {
        const float4* wa = reinterpret_cast<const float4*>(fc1w + k * EMBED + wv * 16);
        const float4* wb = reinterpret_cast<const float4*>(fc1w + k * EMBED + 256 + wv * 16);
        #pragma unroll
        for (int c = 0; c < 4; ++c) {
            float4 w4 = wa[c];                       // uniform -> s_load
            hk[k] = fmaf(w4.x, xa[c].x, hk[k]);
            hk[k] = fmaf(w4.y, xa[c].y, hk[k]);
            hk[k] = fmaf(w4.z, xa[c].z, hk[k]);
            hk[k] = fmaf(w4.w, xa[c].w, hk[k]);
            float4 v4 = wb[c];
            hk[k] = fmaf(v4.x, xb[c].x, hk[k]);
            hk[k] = fmaf(v4.y, xb[c].y, hk[k]);
            hk[k] = fmaf(v4.z, xb[c].z, hk[k]);
            hk[k] = fmaf(v4.w, xb[c].w, hk[k]);
        }
    }
    // write bf16-packed partials: red[wv][t][q] ; row pad 9 -> conflict-free
    #pragma unroll
    for (int q = 0; q < 8; ++q)
        red[wv * 576 + t * 9 + q] = f2b(hk[2 * q]) | (f2b(hk[2 * q + 1]) << 16);
    __syncthreads();

    // ---- reduce h across 16 waves: wave wv handles k = wv for all 64 tokens -
    {
        const int k = wv;
        float s = 0.f;
        #pragma unroll
        for (int wp = 0; wp < 16; ++wp) {
            unsigned pr = red[wp * 576 + t * 9 + (k >> 1)];
            s += b2f((k & 1) ? (pr >> 16) : (pr & 0xFFFFu));
        }
        s = fmaxf(s + fc1b[k], 0.f);
        hs[t * 17 + k] = s;
        if (eh == 0) hbuf[tok * HID + k] = s;        // K3 reads this
    }
    __syncthreads();

    float h[16];
    #pragma unroll
    for (int k = 0; k < 16; ++k) h[k] = hs[t * 17 + k];

    // ---- w1 partial over this block's e-half --------------------------------
    float xr[16];
    if (eh == 0) {
        #pragma unroll
        for (int c = 0; c < 4; ++c) {
            xr[4 * c] = xa[c].x; xr[4 * c + 1] = xa[c].y;
            xr[4 * c + 2] = xa[c].z; xr[4 * c + 3] = xa[c].w;
        }
    } else {
        #pragma unroll
        for (int c = 0; c < 4; ++c) {
            xr[4 * c] = xb[c].x; xr[4 * c + 1] = xb[c].y;
            xr[4 * c + 2] = xb[c].z; xr[4 * c + 3] = xb[c].w;
        }
    }
    const int e0 = eh * 256 + wv * ESL;              // uniform
    float y1[4] = {0.f, 0.f, 0.f, 0.f};
    #pragma unroll
    for (int ei = 0; ei < ESL; ++ei) {
        const float* wr = fc2w + (long)(e0 + ei) * 64;          // 4 rows x 16, uniform
        const float4 b4 = *reinterpret_cast<const float4*>(fc2b + (e0 + ei) * 4);
        float d0 = b4.x, d1 = b4.y, d2 = b4.z, d3 = b4.w;
        #pragma unroll
        for (int k = 0; k < 16; ++k) {
            const float hv = h[k];
            d0 = fmaf(wr[k],      hv, d0);
            d1 = fmaf(wr[16 + k], hv, d1);
            d2 = fmaf(wr[32 + k], hv, d2);
            d3 = fmaf(wr[48 + k], hv, d3);
        }
        const float xv = xr[ei];
        y1[0] = fmaf(xv, d0, y1[0]);
        y1[1] = fmaf(xv, d1, y1[1]);
        y1[2] = fmaf(xv, d2, y1[2]);
        y1[3] = fmaf(xv, d3, y1[3]);
    }

    // ---- reduce y1 across 16 waves, write global partial --------------------
    float* y1red = reinterpret_cast<float*>(red);    // [16][64][5] f32, safe after barrier
    #pragma unroll
    for (int j = 0; j < 4; ++j) y1red[wv * 320 + t * 5 + j] = y1[j];
    __syncthreads();
    if (tid < 256) {
        const int tt = tid >> 2, j = tid & 3;
        float s = 0.f;
        #pragma unroll
        for (int wp = 0; wp < 16; ++wp) s += y1red[wp * 320 + tt * 5 + j];
        y1p[((long)eh * NTOK + g * TG + tt) * 4 + j] = s;
    }
}

// ---------------------------------------------------------------------------
// K3: y1 = relu(part0+part1); w2 generate+consume; relu; transposed store
// grid 256 = (g, eh); block 1024 = 16 waves x 64 lanes(=tokens)
// ---------------------------------------------------------------------------
__global__ __launch_bounds__(1024, 4)
void k3(const float* __restrict__ fc2w, const float* __restrict__ fc2b,
        const float* __restrict__ hbuf, const float* __restrict__ y1p,
        float* __restrict__ out)
{
    __shared__ unsigned short ys[WPB * 64 * 20]; // 41 KB, bf16, row pad 20
    const int tid = threadIdx.x;
    const int t   = tid & 63;
    const int wv  = __builtin_amdgcn_readfirstlane(tid >> 6);
    const int g   = blockIdx.x >> 1;
    const int eh  = blockIdx.x & 1;
    const long tok = (long)g * TG + t;

    float h[16];
    {
        const float4* hp = reinterpret_cast<const float4*>(hbuf + tok * HID);
        #pragma unroll
        for (int c = 0; c < 4; ++c) {
            float4 v = hp[c];
            h[4 * c] = v.x; h[4 * c + 1] = v.y; h[4 * c + 2] = v.z; h[4 * c + 3] = v.w;
        }
    }
    float y1v[4];
    {
        const float4 p0 = *reinterpret_cast<const float4*>(y1p + tok * 4);
        const float4 p1 = *reinterpret_cast<const float4*>(y1p + ((long)NTOK + tok) * 4);
        y1v[0] = fmaxf(p0.x + p1.x, 0.f);
        y1v[1] = fmaxf(p0.y + p1.y, 0.f);
        y1v[2] = fmaxf(p0.z + p1.z, 0.f);
        y1v[3] = fmaxf(p0.w + p1.w, 0.f);
    }

    const int e0 = eh * 256 + wv * ESL;              // uniform
    float yacc[16];
    #pragma unroll
    for (int i = 0; i < 16; ++i) yacc[i] = 0.f;

    #pragma unroll
    for (int j = 0; j < 4; ++j) {
        const float* wr = fc2w + (long)(2048 + j * 512 + e0) * HID;  // 16 contiguous rows
        const float* br = fc2b + 2048 + j * 512 + e0;
        const float yj = y1v[j];
        #pragma unroll
        for (int ei = 0; ei < ESL; ++ei) {
            float d = br[ei];                        // uniform s_load
            #pragma unroll
            for (int k = 0; k < 16; ++k) d = fmaf(wr[ei * 16 + k], h[k], d);
            yacc[ei] = fmaf(yj, d, yacc[ei]);
        }
    }

    // ---- transposed store via per-wave LDS (bf16; threshold 0.995 allows) ---
    #pragma unroll
    for (int q = 0; q < 8; ++q) {
        unsigned pr = f2b(fmaxf(yacc[2 * q], 0.f)) |
                      (f2b(fmaxf(yacc[2 * q + 1], 0.f)) << 16);
        *reinterpret_cast<unsigned*>(&ys[wv * 1280 + t * 20 + q * 2]) = pr;
    }
    __syncthreads();
    {
        const int tq = (tid & 63) >> 2, c = tid & 3;
        #pragma unroll
        for (int it = 0; it < 4; ++it) {
            const int tt = it * 16 + tq;
            uint2 pr = *reinterpret_cast<const uint2*>(&ys[wv * 1280 + tt * 20 + c * 4]);
            float4 o;
            o.x = b2f(pr.x & 0xFFFFu); o.y = b2f(pr.x >> 16);
            o.z = b2f(pr.y & 0xFFFFu); o.w = b2f(pr.y >> 16);
            *reinterpret_cast<float4*>(out + ((long)g * TG + tt) * EMBED + eh * 256 + wv * 16 + c * 4) = o;
        }
    }
}

extern "C" void kernel_launch(void* const* d_in, const int* in_sizes, int n_in,
                              void* d_out, int out_size, void* d_ws, size_t ws_size,
                              hipStream_t stream) {
    const float* x    = (const float*)d_in[0];
    const float* fc1w = (const float*)d_in[1];
    const float* fc1b = (const float*)d_in[2];
    const float* fc2w = (const float*)d_in[3];
    const float* fc2b = (const float*)d_in[4];
    float* out  = (float*)d_out;
    float* hbuf = (float*)d_ws;                      // 8192*16 f32 = 512 KB
    float* y1p  = hbuf + (long)NTOK * HID;           // 2*8192*4 f32 = 256 KB

    k12<<<dim3(256), dim3(1024), 0, stream>>>(x, fc1w, fc1b, fc2w, fc2b, hbuf, y1p);
    k3 <<<dim3(256), dim3(1024), 0, stream>>>(fc2w, fc2b, hbuf, y1p, out);
}

// Round 3
// 27.299 us; speedup vs baseline: 2.6038x; 1.8627x over previous
//
#include <hip/hip_runtime.h>

#define EMBED 512
#define HID 16
#define NTOK 8192
#define MT 16            // tokens per block (one MFMA M-tile)
#define NB1 6            // GEMM1 N-fragments (96 cols = 16 h | 64 G | 4 xb | pad)
#define KS1 16           // GEMM1 K-steps (512/32)
#define NB2 32           // GEMM2 N-fragments (512 cols)
#define KS2 3            // GEMM2 K-steps (96/32; rows 68..95 zero)
#define B1ELEMS (KS1 * NB1 * 64 * 8)   // 49152
#define B2ELEMS (KS2 * NB2 * 64 * 8)   // 49152

typedef __attribute__((ext_vector_type(8))) short short8;  // 8 bf16
typedef __attribute__((ext_vector_type(4))) float f32x4;

#define MFMA(a, b, c) __builtin_amdgcn_mfma_f32_16x16x32_bf16((a), (b), (c), 0, 0, 0)

__device__ __forceinline__ unsigned short f2b(float f) {  // f32 -> bf16 bits, RNE
    unsigned u = __float_as_uint(f);
    return (unsigned short)((u + 0x7FFFu + ((u >> 16) & 1u)) >> 16);
}
__device__ __forceinline__ void split_bf16(float f, short& hi, short& lo) {
    unsigned u = __float_as_uint(f);
    unsigned hb = (u + 0x7FFFu + ((u >> 16) & 1u)) >> 16;
    hi = (short)hb;
    float fh = __uint_as_float(hb << 16);
    lo = (short)f2b(f - fh);
}

// ---------------------------------------------------------------------------
// prep: pack B1 [512 x 96] and B2 [96 x 512] (bf16) in MFMA B-fragment order:
// frag(kstep, nf): lane l supplies B[k = kstep*32 + (l>>4)*8 + i][col = nf*16 + (l&15)]
// stored flat as [kstep][nf][lane][i] -> coalesced short8 per lane in main.
// ---------------------------------------------------------------------------
__global__ __launch_bounds__(256) void prep(const float* __restrict__ fc1w,
                                            const float* __restrict__ fc2w,
                                            const float* __restrict__ fc2b,
                                            unsigned short* __restrict__ b1f,
                                            unsigned short* __restrict__ b2f)
{
    const int i = blockIdx.x * 256 + threadIdx.x;      // 0..49151
    // ---- B1: cols 0-15 fc1w^T | 16-79 W1[e][j][k] | 80-83 b1[e][j] | 84-95 zero
    {
        const int elem = i & 7, lane = (i >> 3) & 63, rest = i >> 9;  // 0..95
        const int nf = rest % NB1, kstep = rest / NB1;
        const int krow = kstep * 32 + (lane >> 4) * 8 + elem;         // e, 0..511
        const int c = nf * 16 + (lane & 15);
        float v;
        if (c < 16)      v = fc1w[c * EMBED + krow];
        else if (c < 80) { int cc = c - 16; v = fc2w[(krow * 4 + (cc >> 4)) * 16 + (cc & 15)]; }
        else if (c < 84) v = fc2b[krow * 4 + (c - 80)];
        else             v = 0.f;
        b1f[i] = f2b(v);
    }
    // ---- B2: rows j*16+k -> W2[j][e][k]; rows 64+j -> b2[j][e]; rows 68-95 zero
    {
        const int elem = i & 7, lane = (i >> 3) & 63, rest = i >> 9;  // 0..95
        const int nf = rest & 31, kstep = rest >> 5;
        const int krow = kstep * 32 + (lane >> 4) * 8 + elem;         // 0..95
        const int e = nf * 16 + (lane & 15);
        float v;
        if (krow < 64)      v = fc2w[(2048 + (krow >> 4) * 512 + e) * 16 + (krow & 15)];
        else if (krow < 68) v = fc2b[2048 + (krow - 64) * 512 + e];
        else                v = 0.f;
        b2f[i] = f2b(v);
    }
}

// ---------------------------------------------------------------------------
// main: per block of 16 tokens: GEMM1 -> glue -> GEMM2. 4 waves, no LDS in GEMMs.
// ---------------------------------------------------------------------------
__global__ __launch_bounds__(256) void hyper_main(const float* __restrict__ x,
                                                  const float* __restrict__ fc1b,
                                                  const unsigned short* __restrict__ b1f,
                                                  const unsigned short* __restrict__ b2f,
                                                  float* __restrict__ out)
{
    __shared__ float c1s[MT][100];          // GEMM1 result spill (pad 100: 2-way max)
    __shared__ unsigned short zhi[MT][104]; // Z hi bf16 (rows 16B-aligned: 208 B)
    __shared__ unsigned short zlo[MT][104]; // Z lo bf16

    const int tid  = threadIdx.x;
    const int lane = tid & 63;
    const int wv   = tid >> 6;
    const int rowA = lane & 15;             // token row inside tile
    const int kgrp = lane >> 4;             // 0..3
    const long tok0 = (long)blockIdx.x * MT;

    // ================= GEMM1: X[16x512] * B1[512x96] =========================
    f32x4 accA = {0.f, 0.f, 0.f, 0.f};
    f32x4 accB = {0.f, 0.f, 0.f, 0.f};
    const int nfA = wv;                     // waves 0-3 -> frags 0-3
    const int nfB = 4 + wv;                 // waves 0-1 -> frags 4-5
    const bool hasB = (wv < 2);

    #pragma unroll 4
    for (int ks = 0; ks < KS1; ++ks) {
        const float* xp = x + (tok0 + rowA) * EMBED + ks * 32 + kgrp * 8;
        float4 a0 = *reinterpret_cast<const float4*>(xp);
        float4 a1 = *reinterpret_cast<const float4*>(xp + 4);
        float av[8] = {a0.x, a0.y, a0.z, a0.w, a1.x, a1.y, a1.z, a1.w};
        short8 ahi, alo;
        #pragma unroll
        for (int q = 0; q < 8; ++q) { short h2, l2; split_bf16(av[q], h2, l2); ahi[q] = h2; alo[q] = l2; }

        short8 bA = *reinterpret_cast<const short8*>(b1f + ((ks * NB1 + nfA) * 64 + lane) * 8);
        accA = MFMA(alo, bA, accA);
        accA = MFMA(ahi, bA, accA);
        if (hasB) {
            short8 bB = *reinterpret_cast<const short8*>(b1f + ((ks * NB1 + nfB) * 64 + lane) * 8);
            accB = MFMA(alo, bB, accB);
            accB = MFMA(ahi, bB, accB);
        }
    }
    // spill C1: lane holds col = nf*16 + (lane&15), rows (lane>>4)*4 + r
    #pragma unroll
    for (int r = 0; r < 4; ++r) c1s[kgrp * 4 + r][nfA * 16 + rowA] = accA[r];
    if (hasB) {
        #pragma unroll
        for (int r = 0; r < 4; ++r) c1s[kgrp * 4 + r][nfB * 16 + rowA] = accB[r];
    }
    __syncthreads();

    // ================= glue: h, y1, Z = (y1 (x) h | y1 | 0) ==================
    if (tid < 64) {
        const int t = tid & 15, j = tid >> 4;
        float h[16];
        #pragma unroll
        for (int k = 0; k < 16; ++k) h[k] = fmaxf(c1s[t][k] + fc1b[k], 0.f);
        float y1 = c1s[t][80 + j];
        #pragma unroll
        for (int k = 0; k < 16; ++k) y1 = fmaf(c1s[t][16 + j * 16 + k], h[k], y1);
        y1 = fmaxf(y1, 0.f);
        #pragma unroll
        for (int k = 0; k < 16; ++k) {
            short h2, l2; split_bf16(y1 * h[k], h2, l2);
            zhi[t][j * 16 + k] = (unsigned short)h2;
            zlo[t][j * 16 + k] = (unsigned short)l2;
        }
        { short h2, l2; split_bf16(y1, h2, l2);
          zhi[t][64 + j] = (unsigned short)h2; zlo[t][64 + j] = (unsigned short)l2; }
        #pragma unroll
        for (int p = 0; p < 7; ++p) { zhi[t][68 + j * 7 + p] = 0; zlo[t][68 + j * 7 + p] = 0; }
    }
    __syncthreads();

    // ================= GEMM2: Z[16x96] * B2[96x512] ==========================
    f32x4 acc2[8];
    #pragma unroll
    for (int f = 0; f < 8; ++f) acc2[f] = (f32x4){0.f, 0.f, 0.f, 0.f};

    #pragma unroll
    for (int ks = 0; ks < KS2; ++ks) {
        short8 ah = *reinterpret_cast<const short8*>(&zhi[rowA][ks * 32 + kgrp * 8]);
        short8 al = *reinterpret_cast<const short8*>(&zlo[rowA][ks * 32 + kgrp * 8]);
        #pragma unroll
        for (int f = 0; f < 8; ++f) {
            short8 b2v = *reinterpret_cast<const short8*>(b2f + ((ks * NB2 + wv * 8 + f) * 64 + lane) * 8);
            acc2[f] = MFMA(al, b2v, acc2[f]);
            acc2[f] = MFMA(ah, b2v, acc2[f]);
        }
    }

    // ================= relu + store ==========================================
    #pragma unroll
    for (int f = 0; f < 8; ++f) {
        const int e = (wv * 8 + f) * 16 + rowA;
        #pragma unroll
        for (int r = 0; r < 4; ++r) {
            out[(tok0 + kgrp * 4 + r) * EMBED + e] = fmaxf(acc2[f][r], 0.f);
        }
    }
}

extern "C" void kernel_launch(void* const* d_in, const int* in_sizes, int n_in,
                              void* d_out, int out_size, void* d_ws, size_t ws_size,
                              hipStream_t stream) {
    const float* x    = (const float*)d_in[0];
    const float* fc1w = (const float*)d_in[1];
    const float* fc1b = (const float*)d_in[2];
    const float* fc2w = (const float*)d_in[3];
    const float* fc2b = (const float*)d_in[4];
    float* out = (float*)d_out;

    unsigned short* b1f = (unsigned short*)d_ws;       // 96 KB
    unsigned short* b2f = b1f + B1ELEMS;               // 96 KB

    prep<<<dim3(B1ELEMS / 256), dim3(256), 0, stream>>>(fc1w, fc2w, fc2b, b1f, b2f);
    hyper_main<<<dim3(NTOK / MT), dim3(256), 0, stream>>>(x, fc1b, b1f, b2f, out);
}

// Round 5
// 26.599 us; speedup vs baseline: 2.6722x; 1.0263x over previous
//
#include <hip/hip_runtime.h>

#define EMBED 512
#define NTOK 8192
#define MT 16            // tokens per block (one MFMA M-tile)
#define NB1 6            // GEMM1 N-fragments (96 cols = 16 h | 64 G | 4 xb | pad)
#define KS1 16           // GEMM1 K-steps (512/32)
#define NB2 32           // GEMM2 N-fragments (512 cols)
#define KS2 3            // GEMM2 K-steps (96/32; rows 68..95 zero)
#define B1ELEMS (KS1 * NB1 * 64 * 8)   // 49152
#define B2ELEMS (KS2 * NB2 * 64 * 8)   // 49152
#define XR 520           // LDS x row pitch (halves): 1040 B == 4 banks mod 32
#define ZR 104           // LDS z row pitch (halves): 208 B == 20 banks mod 32

using half8   = __attribute__((ext_vector_type(8))) _Float16;
using half2_t = __attribute__((ext_vector_type(2))) _Float16;
using f32x4   = __attribute__((ext_vector_type(4))) float;

#define MFMA16(a, b, c) __builtin_amdgcn_mfma_f32_16x16x32_f16((a), (b), (c), 0, 0, 0)

__device__ __forceinline__ half2_t pkrtz(float a, float b) {
    return __builtin_bit_cast(half2_t, __builtin_amdgcn_cvt_pkrtz(a, b));
}

// ---------------------------------------------------------------------------
// prep: pack B1 [512 x 96] and B2 [96 x 512] (f16, RNE) in MFMA B-frag order:
// frag(kstep, nf): lane l supplies B[k = kstep*32 + (l>>4)*8 + i][col = nf*16 + (l&15)]
// flat [kstep][nf][lane][i] -> coalesced 16B/lane in main.
// ---------------------------------------------------------------------------
__global__ __launch_bounds__(256) void prep(const float* __restrict__ fc1w,
                                            const float* __restrict__ fc2w,
                                            const float* __restrict__ fc2b,
                                            _Float16* __restrict__ b1f,
                                            _Float16* __restrict__ b2f)
{
    const int i = blockIdx.x * 256 + threadIdx.x;      // 0..49151
    // ---- B1: cols 0-15 fc1w^T | 16-79 W1[e][j][k] | 80-83 b1[e][j] | 84+ zero
    {
        const int elem = i & 7, lane = (i >> 3) & 63, rest = i >> 9;
        const int nf = rest % NB1, kstep = rest / NB1;
        const int krow = kstep * 32 + (lane >> 4) * 8 + elem;         // e
        const int c = nf * 16 + (lane & 15);
        float v;
        if (c < 16)      v = fc1w[c * EMBED + krow];
        else if (c < 80) { int cc = c - 16; v = fc2w[(krow * 4 + (cc >> 4)) * 16 + (cc & 15)]; }
        else if (c < 84) v = fc2b[krow * 4 + (c - 80)];
        else             v = 0.f;
        b1f[i] = (_Float16)v;
    }
    // ---- B2: rows j*16+k -> W2[j][e][k]; rows 64+j -> b2[j][e]; rows 68+ zero
    {
        const int elem = i & 7, lane = (i >> 3) & 63, rest = i >> 9;
        const int nf = rest & 31, kstep = rest >> 5;
        const int krow = kstep * 32 + (lane >> 4) * 8 + elem;         // 0..95
        const int e = nf * 16 + (lane & 15);
        float v;
        if (krow < 64)      v = fc2w[(2048 + (krow >> 4) * 512 + e) * 16 + (krow & 15)];
        else if (krow < 68) v = fc2b[2048 + (krow - 64) * 512 + e];
        else                v = 0.f;
        b2f[i] = (_Float16)v;
    }
}

// ---------------------------------------------------------------------------
// main: per block of 16 tokens: stage x->f16 LDS; GEMM1 -> glue -> GEMM2.
// ---------------------------------------------------------------------------
__global__ __launch_bounds__(256) void hyper_main(const float* __restrict__ x,
                                                  const float* __restrict__ fc1b,
                                                  const _Float16* __restrict__ b1f,
                                                  const _Float16* __restrict__ b2f,
                                                  float* __restrict__ out)
{
    __shared__ _Float16 xh[MT][XR];         // 16.6 KB f16 x-tile
    __shared__ float    c1s[MT][100];       // 6.4 KB GEMM1 result spill
    __shared__ _Float16 zh[MT][ZR];         // 3.3 KB Z (f16)

    const int tid  = threadIdx.x;
    const int lane = tid & 63;
    const int wv   = tid >> 6;
    const int rowA = lane & 15;             // token row inside tile
    const int kgrp = lane >> 4;             // 0..3
    const long tok0 = (long)blockIdx.x * MT;

    // ---- stage x: 16 x 512 f32 -> f16 LDS (coalesced, converted once) ------
    {
        const float4* xg = reinterpret_cast<const float4*>(x + tok0 * EMBED);
        #pragma unroll
        for (int i = 0; i < 8; ++i) {
            const int idx = tid + i * 256;            // 2048 float4
            float4 v = xg[idx];
            const int t = idx >> 7, e4 = idx & 127;
            half2_t p0 = pkrtz(v.x, v.y), p1 = pkrtz(v.z, v.w);
            uint2 w;
            w.x = __builtin_bit_cast(unsigned, p0);
            w.y = __builtin_bit_cast(unsigned, p1);
            *reinterpret_cast<uint2*>(&xh[t][e4 * 4]) = w;
        }
    }
    __syncthreads();

    // ================= GEMM1: X[16x512] * B1[512x96] =========================
    f32x4 accA = {0.f, 0.f, 0.f, 0.f};
    f32x4 accB = {0.f, 0.f, 0.f, 0.f};
    const int nfA = wv;
    const int nfB = 4 + wv;
    const bool hasB = (wv < 2);

    #pragma unroll
    for (int ks = 0; ks < KS1; ++ks) {
        half8 a = *reinterpret_cast<const half8*>(&xh[rowA][ks * 32 + kgrp * 8]);
        half8 bA = *reinterpret_cast<const half8*>(b1f + ((ks * NB1 + nfA) * 64 + lane) * 8);
        accA = MFMA16(a, bA, accA);
        if (hasB) {
            half8 bB = *reinterpret_cast<const half8*>(b1f + ((ks * NB1 + nfB) * 64 + lane) * 8);
            accB = MFMA16(a, bB, accB);
        }
    }
    #pragma unroll
    for (int r = 0; r < 4; ++r) c1s[kgrp * 4 + r][nfA * 16 + rowA] = accA[r];
    if (hasB) {
        #pragma unroll
        for (int r = 0; r < 4; ++r) c1s[kgrp * 4 + r][nfB * 16 + rowA] = accB[r];
    }
    __syncthreads();

    // ================= glue: h, y1, Z = (y1 (x) h | y1 | 0) ==================
    if (tid < 64) {
        const int t = tid & 15, j = tid >> 4;
        float h[16];
        #pragma unroll
        for (int k = 0; k < 16; ++k) h[k] = fmaxf(c1s[t][k] + fc1b[k], 0.f);
        float y1 = c1s[t][80 + j];
        #pragma unroll
        for (int k = 0; k < 16; ++k) y1 = fmaf(c1s[t][16 + j * 16 + k], h[k], y1);
        y1 = fmaxf(y1, 0.f);
        #pragma unroll
        for (int k = 0; k < 16; k += 2) {
            half2_t p = pkrtz(y1 * h[k], y1 * h[k + 1]);
            *reinterpret_cast<half2_t*>(&zh[t][j * 16 + k]) = p;
        }
        zh[t][64 + j] = (_Float16)y1;
        #pragma unroll
        for (int p = 0; p < 7; ++p) zh[t][68 + j * 7 + p] = (_Float16)0.f;
    }
    __syncthreads();

    // ================= GEMM2: Z[16x96] * B2[96x512] ==========================
    f32x4 acc2[8];
    #pragma unroll
    for (int f = 0; f < 8; ++f) acc2[f] = (f32x4){0.f, 0.f, 0.f, 0.f};

    #pragma unroll
    for (int ks = 0; ks < KS2; ++ks) {
        half8 az = *reinterpret_cast<const half8*>(&zh[rowA][ks * 32 + kgrp * 8]);
        #pragma unroll
        for (int f = 0; f < 8; ++f) {
            half8 bv = *reinterpret_cast<const half8*>(b2f + ((ks * NB2 + wv * 8 + f) * 64 + lane) * 8);
            acc2[f] = MFMA16(az, bv, acc2[f]);
        }
    }

    // ================= relu + store ==========================================
    #pragma unroll
    for (int f = 0; f < 8; ++f) {
        const int e = (wv * 8 + f) * 16 + rowA;
        #pragma unroll
        for (int r = 0; r < 4; ++r) {
            out[(tok0 + kgrp * 4 + r) * EMBED + e] = fmaxf(acc2[f][r], 0.f);
        }
    }
}

extern "C" void kernel_launch(void* const* d_in, const int* in_sizes, int n_in,
                              void* d_out, int out_size, void* d_ws, size_t ws_size,
                              hipStream_t stream) {
    const float* x    = (const float*)d_in[0];
    const float* fc1w = (const float*)d_in[1];
    const float* fc1b = (const float*)d_in[2];
    const float* fc2w = (const float*)d_in[3];
    const float* fc2b = (const float*)d_in[4];
    float* out = (float*)d_out;

    _Float16* b1f = (_Float16*)d_ws;                   // 96 KB
    _Float16* b2f = b1f + B1ELEMS;                     // 96 KB

    prep<<<dim3(B1ELEMS / 256), dim3(256), 0, stream>>>(fc1w, fc2w, fc2b, b1f, b2f);
    hyper_main<<<dim3(NTOK / MT), dim3(256), 0, stream>>>(x, fc1b, b1f, b2f, out);
}